// Round 4
// baseline (483.954 us; speedup 1.0000x reference)
//
#include <hip/hip_runtime.h>
#include <math.h>

#define NEG_SLOPE 0.2f
#define SCAN_CHUNK 1024
#define NPART 8           // dst partitions ~ XCDs (blockIdx & 7 heuristic)

// ---------------- bf16 helpers ----------------
__device__ __forceinline__ unsigned short f2bf(float f) {
    unsigned int u = __float_as_uint(f);
    unsigned int r = (u + 0x7FFFu + ((u >> 16) & 1u)) >> 16;   // RNE
    return (unsigned short)r;
}
__device__ __forceinline__ float bfl(unsigned int u) { return __uint_as_float(u << 16); }
__device__ __forceinline__ float bfh(unsigned int u) { return __uint_as_float(u & 0xffff0000u); }

// ---------------------------------------------------------------------------
// CSR build, XCD-partitioned: counts start at 1 (self-loop), histogram and
// scatter each restrict writes/atomics to a 1/8 dst range so the written
// lines stay in one XCD's L2.
// ---------------------------------------------------------------------------
__global__ void init_ones(int* __restrict__ cnt, int n) {
    int t = blockIdx.x * blockDim.x + threadIdx.x;
    if (t < n) cnt[t] = 1;
}

__global__ void hist_part(const int* __restrict__ ei, int E, int N, int* __restrict__ cnt) {
    int part = blockIdx.x & (NPART - 1);
    int sub  = blockIdx.x >> 3;
    int nb   = gridDim.x >> 3;
    int PR = (N + NPART - 1) / NPART;
    int lo = part * PR, hi = min(N, lo + PR);
    int stride = nb * blockDim.x;
    for (int t = sub * blockDim.x + threadIdx.x; t < E; t += stride) {
        int d = ei[E + t];
        if (d >= lo && d < hi) atomicAdd(&cnt[d], 1);
    }
}

__global__ void scan_part(const int* __restrict__ cnt, int n, int* __restrict__ part) {
    __shared__ int sdata[256];
    int b = blockIdx.x, tid = threadIdx.x;
    int base = b * SCAN_CHUNK;
    int sum = 0;
    for (int i = tid; i < SCAN_CHUNK; i += 256) {
        int idx = base + i;
        sum += (idx < n) ? cnt[idx] : 0;
    }
    sdata[tid] = sum; __syncthreads();
    for (int s = 128; s > 0; s >>= 1) {
        if (tid < s) sdata[tid] += sdata[tid + s];
        __syncthreads();
    }
    if (tid == 0) part[b] = sdata[0];
}

__global__ void scan_tops(int* __restrict__ part, int nb) {
    int lane = threadIdx.x;
    int v0 = (lane < nb) ? part[lane] : 0;
    int i1 = lane + 64;
    int v1 = (i1 < nb) ? part[i1] : 0;
    int o0 = v0, o1 = v1;
    for (int off = 1; off < 64; off <<= 1) {
        int t = __shfl_up(v0, off, 64); if (lane >= off) v0 += t;
        t = __shfl_up(v1, off, 64);     if (lane >= off) v1 += t;
    }
    int tot0 = __shfl(v0, 63, 64);
    if (lane < nb) part[lane] = v0 - o0;
    if (i1 < nb)   part[i1]   = v1 - o1 + tot0;
}

__global__ void scan_final(const int* __restrict__ cnt, int n, int total,
                           const int* __restrict__ part,
                           int* __restrict__ row_ptr, int* __restrict__ cursor) {
    __shared__ int sdata[256];
    int b = blockIdx.x, tid = threadIdx.x;
    int base = b * SCAN_CHUNK + tid * 4;
    int v[4]; int s = 0;
    #pragma unroll
    for (int j = 0; j < 4; ++j) {
        int idx = base + j;
        v[j] = (idx < n) ? cnt[idx] : 0;
        s += v[j];
    }
    sdata[tid] = s; __syncthreads();
    for (int off = 1; off < 256; off <<= 1) {
        int t = (tid >= off) ? sdata[tid - off] : 0;
        __syncthreads();
        sdata[tid] += t;
        __syncthreads();
    }
    int run = part[b] + sdata[tid] - s;
    #pragma unroll
    for (int j = 0; j < 4; ++j) {
        int idx = base + j;
        if (idx < n) { row_ptr[idx] = run; cursor[idx] = run; }
        run += v[j];
    }
    if (b == 0 && tid == 0) row_ptr[n] = total;
}

__global__ void scatter_part(const int* __restrict__ ei, int E, int N,
                             int* __restrict__ cursor, int* __restrict__ col) {
    int part = blockIdx.x & (NPART - 1);
    int sub  = blockIdx.x >> 3;
    int nb   = gridDim.x >> 3;
    int PR = (N + NPART - 1) / NPART;
    int lo = part * PR, hi = min(N, lo + PR);
    int total = E + N;
    int stride = nb * blockDim.x;
    for (int t = sub * blockDim.x + threadIdx.x; t < total; t += stride) {
        int s, d;
        if (t < E) { s = ei[t]; d = ei[E + t]; }
        else       { s = d = t - E; }
        if (d >= lo && d < hi) {
            int pos = atomicAdd(&cursor[d], 1);
            col[pos] = s;
        }
    }
}

// ---------------------------------------------------------------------------
// GEMM (K x 64) + alpha epilogue (unchanged from round 3).
// ---------------------------------------------------------------------------
template<int K, int CH>   // CH channels/head; H = 64/CH
__global__ void gemm_alpha(const float* __restrict__ A, const float* __restrict__ W,
                           const float* __restrict__ a_src, const float* __restrict__ a_dst,
                           unsigned short* __restrict__ Hb, float* __restrict__ AS,
                           float* __restrict__ AD, int N) {
    __shared__ float Wl[K * 64];
    const int tid = threadIdx.x;
    for (int i = tid; i < K * 16; i += 256)
        ((float4*)Wl)[i] = ((const float4*)W)[i];
    const int lane = tid & 63, wave = tid >> 6;
    const int l16 = lane & 15, nsub = lane >> 4;
    const int col4 = l16 * 4;
    const int H = 64 / CH;
    const float4 as4 = *(const float4*)&a_src[col4];
    const float4 ad4 = *(const float4*)&a_dst[col4];
    __syncthreads();
    for (int n0 = (blockIdx.x * 4 + wave) * 4; n0 < N; n0 += gridDim.x * 16) {
        int n = n0 + nsub;
        bool ok = n < N;
        const float* Arow = A + (size_t)(ok ? n : n0) * K;
        float4 acc = {0.f, 0.f, 0.f, 0.f};
        #pragma unroll 4
        for (int k4 = 0; k4 < K; k4 += 4) {
            float4 a = *(const float4*)&Arow[k4];
            float4 w0 = *(const float4*)&Wl[(k4 + 0) * 64 + col4];
            float4 w1 = *(const float4*)&Wl[(k4 + 1) * 64 + col4];
            float4 w2 = *(const float4*)&Wl[(k4 + 2) * 64 + col4];
            float4 w3 = *(const float4*)&Wl[(k4 + 3) * 64 + col4];
            acc.x = fmaf(a.x, w0.x, acc.x); acc.y = fmaf(a.x, w0.y, acc.y);
            acc.z = fmaf(a.x, w0.z, acc.z); acc.w = fmaf(a.x, w0.w, acc.w);
            acc.x = fmaf(a.y, w1.x, acc.x); acc.y = fmaf(a.y, w1.y, acc.y);
            acc.z = fmaf(a.y, w1.z, acc.z); acc.w = fmaf(a.y, w1.w, acc.w);
            acc.x = fmaf(a.z, w2.x, acc.x); acc.y = fmaf(a.z, w2.y, acc.y);
            acc.z = fmaf(a.z, w2.z, acc.z); acc.w = fmaf(a.z, w2.w, acc.w);
            acc.x = fmaf(a.w, w3.x, acc.x); acc.y = fmaf(a.w, w3.y, acc.y);
            acc.z = fmaf(a.w, w3.z, acc.z); acc.w = fmaf(a.w, w3.w, acc.w);
        }
        if (ok) {
            union { unsigned short u[4]; uint2 v; } pk;
            pk.u[0] = f2bf(acc.x); pk.u[1] = f2bf(acc.y);
            pk.u[2] = f2bf(acc.z); pk.u[3] = f2bf(acc.w);
            *(uint2*)&Hb[(size_t)n * 64 + col4] = pk.v;
            float vs = acc.x * as4.x + acc.y * as4.y + acc.z * as4.z + acc.w * as4.w;
            float vd = acc.x * ad4.x + acc.y * ad4.y + acc.z * ad4.z + acc.w * ad4.w;
            #pragma unroll
            for (int off = 1; off < CH / 4; off <<= 1) {
                vs += __shfl_xor(vs, off, 64);
                vd += __shfl_xor(vd, off, 64);
            }
            if ((l16 & (CH / 4 - 1)) == 0) {
                int h = col4 / CH;
                AS[(size_t)n * H + h] = vs;
                AD[(size_t)n * H + h] = vd;
            }
        }
    }
}

// ---------------------------------------------------------------------------
// Single-pass softmax aggregation. One wave per dst node; chunk of 64 edges;
// FIXED 8-trip unrolled inner loop (masked) so all 16 gathers of a chunk are
// in flight before the first use -> latency-hiding instead of 3 serial rounds.
// ---------------------------------------------------------------------------
template<int H, bool FINAL>
__global__ void aggregate(const int* __restrict__ row_ptr, const int* __restrict__ col,
                          const float* __restrict__ AS, const float* __restrict__ AD,
                          const uint4* __restrict__ Hb, const float* __restrict__ bias,
                          float* __restrict__ OUT, int N) {
    const int CH = 64 / H;
    int lane = threadIdx.x & 63;
    int wid = (blockIdx.x * blockDim.x + threadIdx.x) >> 6;
    int nw = (gridDim.x * blockDim.x) >> 6;
    int slot = lane >> 3, l8 = lane & 7;
    int h = (l8 * 8) / CH;                 // H=8 -> l8 ; H=1 -> 0
    float4 b4a = *(const float4*)&bias[l8 * 8];
    float4 b4b = *(const float4*)&bias[l8 * 8 + 4];
    for (int n = wid; n < N; n += nw) {
        int beg = row_ptr[n], end = row_ptr[n + 1];
        float ad = AD[(size_t)n * H + h];
        float den = 0.0f;
        float acc[8] = {0.f, 0.f, 0.f, 0.f, 0.f, 0.f, 0.f, 0.f};
        for (int base = beg; base < end; base += 64) {
            int cnt = min(64, end - base);
            int myc = (lane < cnt) ? col[base + lane] : 0;
            #pragma unroll
            for (int j = 0; j < 8; ++j) {
                int idx = j * 8 + slot;
                int s = __shfl(myc, idx, 64);   // masked lanes carry s=0 (hot line)
                float e = AS[(size_t)s * H + h] + ad;
                e = e > 0.0f ? e : NEG_SLOPE * e;
                float p = __expf(e);
                p = (idx < cnt) ? p : 0.0f;
                den += p;
                uint4 hv = Hb[(size_t)s * 8 + l8];
                acc[0] = fmaf(p, bfl(hv.x), acc[0]);
                acc[1] = fmaf(p, bfh(hv.x), acc[1]);
                acc[2] = fmaf(p, bfl(hv.y), acc[2]);
                acc[3] = fmaf(p, bfh(hv.y), acc[3]);
                acc[4] = fmaf(p, bfl(hv.z), acc[4]);
                acc[5] = fmaf(p, bfh(hv.z), acc[5]);
                acc[6] = fmaf(p, bfl(hv.w), acc[6]);
                acc[7] = fmaf(p, bfh(hv.w), acc[7]);
            }
        }
        #pragma unroll
        for (int off = 8; off <= 32; off <<= 1) {
            den += __shfl_xor(den, off, 64);
            #pragma unroll
            for (int i = 0; i < 8; ++i) acc[i] += __shfl_xor(acc[i], off, 64);
        }
        float inv = 1.0f / (den + 1e-16f);
        float v[8];
        v[0] = acc[0] * inv + b4a.x; v[1] = acc[1] * inv + b4a.y;
        v[2] = acc[2] * inv + b4a.z; v[3] = acc[3] * inv + b4a.w;
        v[4] = acc[4] * inv + b4b.x; v[5] = acc[5] * inv + b4b.y;
        v[6] = acc[6] * inv + b4b.z; v[7] = acc[7] * inv + b4b.w;
        if (!FINAL) {
            #pragma unroll
            for (int i = 0; i < 8; ++i) v[i] = v[i] > 0.0f ? v[i] : __expf(v[i]) - 1.0f;
            if (slot == 0) {
                float4 o0 = {v[0], v[1], v[2], v[3]}, o1 = {v[4], v[5], v[6], v[7]};
                *(float4*)&OUT[(size_t)n * 64 + l8 * 8] = o0;
                *(float4*)&OUT[(size_t)n * 64 + l8 * 8 + 4] = o1;
            }
        } else {
            float m = v[0];
            #pragma unroll
            for (int i = 1; i < 8; ++i) m = fmaxf(m, v[i]);
            #pragma unroll
            for (int off = 1; off <= 4; off <<= 1) m = fmaxf(m, __shfl_xor(m, off, 64));
            float ss = 0.0f;
            #pragma unroll
            for (int i = 0; i < 8; ++i) ss += __expf(v[i] - m);
            #pragma unroll
            for (int off = 1; off <= 4; off <<= 1) ss += __shfl_xor(ss, off, 64);
            float lse = m + __logf(ss);
            if (slot == 0) {
                float4 o0 = {v[0] - lse, v[1] - lse, v[2] - lse, v[3] - lse};
                float4 o1 = {v[4] - lse, v[5] - lse, v[6] - lse, v[7] - lse};
                *(float4*)&OUT[(size_t)n * 64 + l8 * 8] = o0;
                *(float4*)&OUT[(size_t)n * 64 + l8 * 8 + 4] = o1;
            }
        }
    }
}

// ---------------------------------------------------------------------------
extern "C" void kernel_launch(void* const* d_in, const int* in_sizes, int n_in,
                              void* d_out, int out_size, void* d_ws, size_t ws_size,
                              hipStream_t stream) {
    const float* x    = (const float*)d_in[0];
    const int*   ei   = (const int*)d_in[1];
    const float* W1   = (const float*)d_in[2];
    const float* as1w = (const float*)d_in[3];
    const float* ad1w = (const float*)d_in[4];
    const float* b1   = (const float*)d_in[5];
    const float* W2   = (const float*)d_in[6];
    const float* as2w = (const float*)d_in[7];
    const float* ad2w = (const float*)d_in[8];
    const float* b2   = (const float*)d_in[9];
    const int N = in_sizes[0] / 128;   // 100000
    const int E = in_sizes[1] / 2;     // 1600000
    const int total = E + N;
    const int NB = (N + SCAN_CHUNK - 1) / SCAN_CHUNK;

    float* ws = (float*)d_ws;
    size_t N64 = (size_t)N * 64, N8 = (size_t)N * 8;
    size_t off = 0;
    float* AGG1 = ws + off; off += N64;            // elu(layer-1 out), fp32
    unsigned short* h1b = (unsigned short*)(ws + off); off += N64 / 2;  // bf16 rows
    unsigned short* h2b = (unsigned short*)(ws + off); off += N64 / 2;
    float* AS1  = ws + off; off += N8;
    float* AD1  = ws + off; off += N8;
    float* AS2  = ws + off; off += N;
    float* AD2  = ws + off; off += N;
    int* row_ptr = (int*)(ws + off);               // N+1
    int* cursor  = row_ptr + (N + 1);              // N
    int* col     = cursor + N;                     // E+N
    int* part    = col + total;                    // 128

    // ---- CSR build (XCD-partitioned; shared by both layers) ----
    init_ones<<<(N + 255) / 256, 256, 0, stream>>>(cursor, N);   // self-loop counts
    hist_part<<<8 * 96, 256, 0, stream>>>(ei, E, N, cursor);
    scan_part<<<NB, 256, 0, stream>>>(cursor, N, part);
    scan_tops<<<1, 64, 0, stream>>>(part, NB);
    scan_final<<<NB, 256, 0, stream>>>(cursor, N, total, part, row_ptr, cursor);
    scatter_part<<<8 * 96, 256, 0, stream>>>(ei, E, N, cursor, col);

    // ---- layer 1 ----
    gemm_alpha<128, 8><<<2048, 256, 0, stream>>>(x, W1, as1w, ad1w, h1b, AS1, AD1, N);
    aggregate<8, false><<<(N + 3) / 4, 256, 0, stream>>>(row_ptr, col, AS1, AD1,
                                                         (const uint4*)h1b, b1, AGG1, N);
    // ---- layer 2 ----
    gemm_alpha<64, 64><<<2048, 256, 0, stream>>>(AGG1, W2, as2w, ad2w, h2b, AS2, AD2, N);
    aggregate<1, true><<<(N + 3) / 4, 256, 0, stream>>>(row_ptr, col, AS2, AD2,
                                                        (const uint4*)h2b, b2, (float*)d_out, N);
}